// Round 2
// baseline (7692.631 us; speedup 1.0000x reference)
//
#include <hip/hip_runtime.h>
#include <math.h>

#define Hh 128
#define Ww 256
#define Dd 768
#define NPLANE 256            // B*H
#define WF 129                // W/2+1
#define SFREQ (WF*Dd)         // 99072
#define NPOS (2*Hh*WF)        // 33024
#define LAMBDA_SS 0.01f

typedef short short8 __attribute__((ext_vector_type(8)));
typedef float floatx4 __attribute__((ext_vector_type(4)));

__device__ __forceinline__ float bf2f(ushort u) {
    union { unsigned int i; float f; } v; v.i = ((unsigned int)u) << 16; return v.f;
}
__device__ __forceinline__ ushort f2bf(float f) {
    union { float f; unsigned int i; } v; v.f = f;
    unsigned int r = v.i + 0x7fffu + ((v.i >> 16) & 1u);   // RTNE
    return (ushort)(r >> 16);
}

// ------------------------------------------------- LayerNorm: fp32 in, bf16 out
__global__ __launch_bounds__(256) void ln_kernel(const float* __restrict__ x,
        const float* __restrict__ g, const float* __restrict__ b,
        ushort* __restrict__ out) {
    int row = blockIdx.x;
    int tid = threadIdx.x;
    const float* xr = x + (size_t)row * Dd;
    float v0 = xr[tid], v1 = xr[tid + 256], v2 = xr[tid + 512];
    __shared__ float red[256];
    red[tid] = v0 + v1 + v2;
    __syncthreads();
    for (int o = 128; o > 0; o >>= 1) { if (tid < o) red[tid] += red[tid + o]; __syncthreads(); }
    float mean = red[0] * (1.0f / 768.0f);
    __syncthreads();
    float d0 = v0 - mean, d1 = v1 - mean, d2 = v2 - mean;
    red[tid] = d0 * d0 + d1 * d1 + d2 * d2;
    __syncthreads();
    for (int o = 128; o > 0; o >>= 1) { if (tid < o) red[tid] += red[tid + o]; __syncthreads(); }
    float inv = rsqrtf(red[0] * (1.0f / 768.0f) + 1e-5f);
    ushort* orow = out + (size_t)row * Dd;
    orow[tid]       = f2bf(d0 * inv * g[tid]       + b[tid]);
    orow[tid + 256] = f2bf(d1 * inv * g[tid + 256] + b[tid + 256]);
    orow[tid + 512] = f2bf(d2 * inv * g[tid + 512] + b[tid + 512]);
}

// ------------------------------------------------- forward real DFT along W
// in:  spatial [plane(256)][w(256)][d(768)] bf16
// out: Fr/Fi   [plane][wf(129)][d] bf16, tw = e^{-2pi i w wf/256}, scale 1/16
__global__ __launch_bounds__(256) void dft_w_fwd_kernel(const ushort* __restrict__ X,
        ushort* __restrict__ Fr, ushort* __restrict__ Fi) {
    int d = blockIdx.x * 256 + threadIdx.x;
    int wf0 = blockIdx.y * 4;
    int p = blockIdx.z;
    const ushort* xp = X + (size_t)p * Ww * Dd + d;
    float twr[4], twi[4], sr[4], si[4], ar[4], ai[4];
#pragma unroll
    for (int q = 0; q < 4; ++q) {
        float ang = (float)(-2.0 * M_PI * (double)(wf0 + q) / 256.0);
        sincosf(ang, &si[q], &sr[q]);
        twr[q] = 1.0f; twi[q] = 0.0f; ar[q] = 0.0f; ai[q] = 0.0f;
    }
    for (int w = 0; w < Ww; ++w) {
        float xv = bf2f(xp[(size_t)w * Dd]);
#pragma unroll
        for (int q = 0; q < 4; ++q) {
            ar[q] += xv * twr[q];
            ai[q] += xv * twi[q];
            float nr = twr[q] * sr[q] - twi[q] * si[q];
            twi[q]  = twr[q] * si[q] + twi[q] * sr[q];
            twr[q]  = nr;
        }
    }
#pragma unroll
    for (int q = 0; q < 4; ++q) {
        int wf = wf0 + q;
        if (wf < WF) {
            size_t o = (size_t)p * SFREQ + (size_t)wf * Dd + d;
            Fr[o] = f2bf(ar[q] * 0.0625f);
            Fi[o] = f2bf(ai[q] * 0.0625f);
        }
    }
}

// ------------------------------------------- complex DFT along H (fwd/inv)
// in/out: [b(2)][h(128)][col(SFREQ)] bf16; tw = e^{sign*2pi i h hf/128}, scale 1/sqrt(128)
__global__ __launch_bounds__(256) void dft_h_kernel(const ushort* __restrict__ Ir,
        const ushort* __restrict__ Ii, ushort* __restrict__ Or, ushort* __restrict__ Oi,
        float sign) {
    int col = blockIdx.x * 256 + threadIdx.x;
    int hf0 = blockIdx.y * 4;
    int b = blockIdx.z;
    const ushort* ir = Ir + (size_t)b * Hh * SFREQ + col;
    const ushort* ii = Ii + (size_t)b * Hh * SFREQ + col;
    float twr[4], twi[4], sr[4], si[4], ar[4], ai[4];
#pragma unroll
    for (int q = 0; q < 4; ++q) {
        float ang = sign * (float)(2.0 * M_PI * (double)(hf0 + q) / 128.0);
        sincosf(ang, &si[q], &sr[q]);
        twr[q] = 1.0f; twi[q] = 0.0f; ar[q] = 0.0f; ai[q] = 0.0f;
    }
    for (int h = 0; h < Hh; ++h) {
        float vr = bf2f(ir[(size_t)h * SFREQ]);
        float vi = bf2f(ii[(size_t)h * SFREQ]);
#pragma unroll
        for (int q = 0; q < 4; ++q) {
            ar[q] += vr * twr[q] - vi * twi[q];
            ai[q] += vr * twi[q] + vi * twr[q];
            float nr = twr[q] * sr[q] - twi[q] * si[q];
            twi[q]  = twr[q] * si[q] + twi[q] * sr[q];
            twr[q]  = nr;
        }
    }
    const float sc = 0.08838834764831845f;  // 1/sqrt(128)
#pragma unroll
    for (int q = 0; q < 4; ++q) {
        size_t o = (size_t)b * Hh * SFREQ + (size_t)(hf0 + q) * SFREQ + col;
        Or[o] = f2bf(ar[q] * sc);
        Oi[o] = f2bf(ai[q] * sc);
    }
}

// --------------------------------------------- inverse real DFT along W
// in: Hr/Hi [plane][wf(129)][d] bf16; out spatial fp32 [plane][w(256)][d]
// x[w] = (2/16) * sum_{wf} c_wf*(hr*cos - hi*sin), c=0.5 at wf=0,128 else 1
__global__ __launch_bounds__(256) void dft_w_inv_kernel(const ushort* __restrict__ Hr,
        const ushort* __restrict__ Hi, float* __restrict__ out) {
    int d = blockIdx.x * 256 + threadIdx.x;
    int w0 = blockIdx.y * 4;
    int p = blockIdx.z;
    const ushort* hr_ = Hr + (size_t)p * SFREQ + d;
    const ushort* hi_ = Hi + (size_t)p * SFREQ + d;
    float twr[4], twi[4], sr[4], si[4], acc[4];
#pragma unroll
    for (int q = 0; q < 4; ++q) {
        float ang = (float)(2.0 * M_PI * (double)(w0 + q) / 256.0);
        sincosf(ang, &si[q], &sr[q]);
        twr[q] = 1.0f; twi[q] = 0.0f; acc[q] = 0.0f;
    }
    for (int wf = 0; wf < WF; ++wf) {
        float vr = bf2f(hr_[(size_t)wf * Dd]);
        float vi = bf2f(hi_[(size_t)wf * Dd]);
        float wt = (wf == 0 || wf == 128) ? 0.5f : 1.0f;
        vr *= wt; vi *= wt;
#pragma unroll
        for (int q = 0; q < 4; ++q) {
            acc[q] += vr * twr[q] - vi * twi[q];
            float nr = twr[q] * sr[q] - twi[q] * si[q];
            twi[q]  = twr[q] * si[q] + twi[q] * sr[q];
            twr[q]  = nr;
        }
    }
#pragma unroll
    for (int q = 0; q < 4; ++q)
        out[(size_t)p * Ww * Dd + (size_t)(w0 + q) * Dd + d] = acc[q] * 0.125f;
}

// ------------------------------------------------- block-diag channel mixing
// out_n = act( sum_m xr*wr -/+ xi*wi + bias );  w fp32: [2][8][96][96], bias fp32: [2][8][96]
__global__ __launch_bounds__(256) void mix_kernel(const ushort* __restrict__ Xr,
        const ushort* __restrict__ Xi, const float* __restrict__ w,
        const float* __restrict__ bias, ushort* __restrict__ Or,
        ushort* __restrict__ Oi, int shrink) {
    int t = blockIdx.x * 256 + threadIdx.x;     // < 33024*768
    int pos = t / 768;
    int ch = t - pos * 768;
    int l = ch / 96;
    int n = ch - l * 96;
    const float* wr = w + (size_t)l * 96 * 96 + n;          // w[0][l][m][n]
    const float* wi = wr + 8 * 96 * 96;                     // w[1][l][m][n]
    const ushort* xr = Xr + (size_t)pos * 768 + l * 96;
    const ushort* xi = Xi + (size_t)pos * 768 + l * 96;
    float ar = 0.0f, ai = 0.0f;
#pragma unroll 4
    for (int m = 0; m < 96; ++m) {
        float xrv = bf2f(xr[m]), xiv = bf2f(xi[m]);
        float wrv = wr[(size_t)m * 96], wiv = wi[(size_t)m * 96];
        ar += xrv * wrv - xiv * wiv;
        ai += xrv * wiv + xiv * wrv;
    }
    ar += bias[l * 96 + n];
    ai += bias[768 + l * 96 + n];
    if (shrink) { ar = fmaxf(ar - LAMBDA_SS, 0.0f); ai = fmaxf(ai - LAMBDA_SS, 0.0f); }
    else        { ar = fmaxf(ar, 0.0f);             ai = fmaxf(ai, 0.0f); }
    Or[t] = f2bf(ar);
    Oi[t] = f2bf(ai);
}

// ------------------------------------- fp32 -> bf16 transpose [R][C] -> [C][R]
__global__ __launch_bounds__(256) void transpose_kernel(const float* __restrict__ in,
        ushort* __restrict__ out, int R, int C) {
    __shared__ float tile[32][33];
    int c0 = blockIdx.x * 32, r0 = blockIdx.y * 32;
    int tx = threadIdx.x, ty = threadIdx.y;
    for (int j = 0; j < 32; j += 8)
        tile[ty + j][tx] = in[(size_t)(r0 + ty + j) * C + c0 + tx];
    __syncthreads();
    for (int j = 0; j < 32; j += 8)
        out[(size_t)(c0 + ty + j) * R + r0 + tx] = f2bf(tile[tx][ty + j]);
}

// --------------------------------------------------------------- MFMA GEMM
// C[M,N] = act(A[M,K] * Bt[N,K]^T + bias[col]).  A,Bt bf16; bias fp32.
// out_f32==0: C bf16. out_f32==1: C fp32 += resid.
#define GBM 128
#define GBN 128
#define GBK 32
__global__ __launch_bounds__(256) void gemm_bt_kernel(const ushort* __restrict__ A,
        const ushort* __restrict__ Bt, void* __restrict__ Cv, int M, int N, int K,
        const float* __restrict__ bias, const float* __restrict__ resid,
        int act, int out_f32) {
    __shared__ __align__(16) ushort As[GBM * GBK];
    __shared__ __align__(16) ushort Bs[GBN * GBK];
    int tid = threadIdx.x;
    int bm = blockIdx.y * GBM, bn = blockIdx.x * GBN;
    int wave = tid >> 6, lane = tid & 63;
    int wy = wave >> 1, wx = wave & 1;
    int quad = lane >> 4, l16 = lane & 15;
    int sr = tid >> 2;              // staging row 0..63
    int sc = (tid & 3) * 8;         // staging k offset (8 bf16 = 16B)
    const ushort* Ag = A + (size_t)(bm + sr) * K + sc;
    const ushort* Bg = Bt + (size_t)(bn + sr) * K + sc;

    floatx4 acc[4][4];
#pragma unroll
    for (int i = 0; i < 4; ++i)
#pragma unroll
        for (int j = 0; j < 4; ++j) { acc[i][j][0] = 0.f; acc[i][j][1] = 0.f; acc[i][j][2] = 0.f; acc[i][j][3] = 0.f; }

    for (int k0 = 0; k0 < K; k0 += GBK) {
        uint4 a0 = *(const uint4*)(Ag + k0);
        uint4 a1 = *(const uint4*)(Ag + (size_t)64 * K + k0);
        uint4 b0 = *(const uint4*)(Bg + k0);
        uint4 b1 = *(const uint4*)(Bg + (size_t)64 * K + k0);
        __syncthreads();
        *(uint4*)&As[sr * GBK + sc] = a0;
        *(uint4*)&As[(sr + 64) * GBK + sc] = a1;
        *(uint4*)&Bs[sr * GBK + sc] = b0;
        *(uint4*)&Bs[(sr + 64) * GBK + sc] = b1;
        __syncthreads();
        short8 af[4], bfv[4];
#pragma unroll
        for (int i = 0; i < 4; ++i)
            af[i] = *(const short8*)&As[(wy * 64 + i * 16 + l16) * GBK + quad * 8];
#pragma unroll
        for (int j = 0; j < 4; ++j)
            bfv[j] = *(const short8*)&Bs[(wx * 64 + j * 16 + l16) * GBK + quad * 8];
#pragma unroll
        for (int i = 0; i < 4; ++i)
#pragma unroll
            for (int j = 0; j < 4; ++j)
                acc[i][j] = __builtin_amdgcn_mfma_f32_16x16x32_bf16(af[i], bfv[j], acc[i][j], 0, 0, 0);
    }

#pragma unroll
    for (int i = 0; i < 4; ++i) {
        int row0 = bm + wy * 64 + i * 16 + quad * 4;
#pragma unroll
        for (int j = 0; j < 4; ++j) {
            int col = bn + wx * 64 + j * 16 + l16;
            float bv = bias ? bias[col] : 0.0f;
#pragma unroll
            for (int r = 0; r < 4; ++r) {
                float v = acc[i][j][r] + bv;
                if (act == 1) v = 0.5f * v * (1.0f + erff(v * 0.70710678118f));  // exact GELU
                size_t o = (size_t)(row0 + r) * N + col;
                if (out_f32) {
                    float vv = v + (resid ? resid[o] : 0.0f);
                    ((float*)Cv)[o] = vv;
                } else {
                    ((ushort*)Cv)[o] = f2bf(v);
                }
            }
        }
    }
}

// ---------------------------------------------------------------- launcher
extern "C" void kernel_launch(void* const* d_in, const int* in_sizes, int n_in,
                              void* d_out, int out_size, void* d_ws, size_t ws_size,
                              hipStream_t stream) {
    const float* x    = (const float*)d_in[0];
    const float* n1g  = (const float*)d_in[1];
    const float* n1b  = (const float*)d_in[2];
    const float* w1   = (const float*)d_in[3];
    const float* w2   = (const float*)d_in[4];
    const float* b1   = (const float*)d_in[5];
    const float* b2   = (const float*)d_in[6];
    const float* n2g  = (const float*)d_in[7];
    const float* n2b  = (const float*)d_in[8];
    const float* fc1w = (const float*)d_in[9];
    const float* fc1b = (const float*)d_in[10];
    const float* fc2w = (const float*)d_in[11];
    const float* fc2b = (const float*)d_in[12];
    float*  outf = (float*)d_out;
    ushort* outu = (ushort*)d_out;   // d_out (201 MB fp32) doubles as bf16 scratch

    // ws layout (bf16 elements), total ~161 MB:
    ushort* ws  = (ushort*)d_ws;
    ushort* W1t = ws;                               // [3072][768]
    ushort* W2t = W1t + (size_t)3072 * 768;         // [768][3072]
    ushort* Fr  = W2t + (size_t)768 * 3072;         // [256][129][768]
    ushort* Fi  = Fr + (size_t)NPLANE * SFREQ;
    ushort* hid = Fi + (size_t)NPLANE * SFREQ;      // [8192][3072]
    ushort* Abf = Fr;                               // alias: LN2 out (Fr/Fi dead by then)
    // d_out-resident bf16 scratch:
    ushort* S1  = outu;                             // LN1 out [65536][768]
    ushort* Gr  = outu;                             // [256][129][768] (S1 dead)
    ushort* Gi  = outu + (size_t)NPLANE * SFREQ;

    // weight transposes (Bt layout for gemm_bt)
    transpose_kernel<<<dim3(3072 / 32, 768 / 32), dim3(32, 8), 0, stream>>>(fc1w, W1t, 768, 3072);
    transpose_kernel<<<dim3(768 / 32, 3072 / 32), dim3(32, 8), 0, stream>>>(fc2w, W2t, 3072, 768);

    // LN1: x (fp32) -> S1 (bf16, in d_out storage)
    ln_kernel<<<65536, 256, 0, stream>>>(x, n1g, n1b, S1);

    // rfft2 (ortho)
    dft_w_fwd_kernel<<<dim3(3, 33, NPLANE), 256, 0, stream>>>(S1, Fr, Fi);
    dft_h_kernel<<<dim3(SFREQ / 256, 32, 2), 256, 0, stream>>>(Fr, Fi, Gr, Gi, -1.0f);

    // block-diagonal complex MLP in frequency domain
    mix_kernel<<<(NPOS * 768) / 256, 256, 0, stream>>>(Gr, Gi, w1, b1, Fr, Fi, 0);
    mix_kernel<<<(NPOS * 768) / 256, 256, 0, stream>>>(Fr, Fi, w2, b2, Gr, Gi, 1);

    // irfft2 (ortho): inverse H, then inverse real W -> d_out fp32 spatial
    dft_h_kernel<<<dim3(SFREQ / 256, 32, 2), 256, 0, stream>>>(Gr, Gi, Fr, Fi, 1.0f);
    dft_w_inv_kernel<<<dim3(3, 64, NPLANE), 256, 0, stream>>>(Fr, Fi, outf);

    // LN2: d_out fp32 spatial -> Abf bf16 (ws)
    ln_kernel<<<65536, 256, 0, stream>>>(outf, n2g, n2b, Abf);

    // MLP: gelu(h@fc1+b1) @ fc2 + b2 + residual -> d_out fp32
    const int CH = 8192;
    for (int c = 0; c < 8; ++c) {
        const ushort* Aln = Abf + (size_t)c * CH * 768;
        gemm_bt_kernel<<<dim3(3072 / GBN, CH / GBM), 256, 0, stream>>>(
            Aln, W1t, hid, CH, 3072, 768, fc1b, nullptr, 1, 0);
        gemm_bt_kernel<<<dim3(768 / GBN, CH / GBM), 256, 0, stream>>>(
            hid, W2t, outf + (size_t)c * CH * 768, CH, 768, 3072, fc2b,
            x + (size_t)c * CH * 768, 0, 1);
    }
}